// Round 1
// baseline (1764.461 us; speedup 1.0000x reference)
//
#include <hip/hip_runtime.h>
#include <math.h>

#define BB 32
#define CC 128
#define HH 64
#define WW 64
#define KK 4
#define OO 256
#define RED 32
#define HWSZ (HH*WW)
#define KSTRIDE (OO*CC*9)   // stride between k-slices of weights

// ---------------- Kernel 1: global average pool ----------------
// grid = B*C blocks, 256 threads. Each block reduces one [H,W] plane.
__global__ void pool_kernel(const float* __restrict__ x, float* __restrict__ pooled) {
    int bc = blockIdx.x;
    const float4* p4 = (const float4*)(x + (size_t)bc * HWSZ);
    int tid = threadIdx.x;
    float s = 0.f;
    for (int i = tid; i < HWSZ / 4; i += 256) {
        float4 v = p4[i];
        s += v.x + v.y + v.z + v.w;
    }
    for (int off = 32; off > 0; off >>= 1) s += __shfl_down(s, off, 64);
    __shared__ float reds[4];
    int wid = tid >> 6, lane = tid & 63;
    if (lane == 0) reds[wid] = s;
    __syncthreads();
    if (tid == 0) {
        pooled[bc] = (reds[0] + reds[1] + reds[2] + reds[3]) * (1.0f / HWSZ);
    }
}

// ---------------- Kernel 2: MLP + softmax -> att[B][K] ----------------
// 1 block, 64 threads (one thread per sample, 32 active).
__global__ void att_kernel(const float* __restrict__ pooled,
                           const float* __restrict__ w1, const float* __restrict__ b1,
                           const float* __restrict__ w2, const float* __restrict__ b2,
                           float* __restrict__ att) {
    int b = threadIdx.x;
    if (b >= BB) return;
    const float* pb = pooled + b * CC;
    float hbuf[RED];
    for (int r = 0; r < RED; ++r) {
        float acc = b1[r];
        const float* w1r = w1 + r * CC;
        for (int c = 0; c < CC; ++c) acc = fmaf(pb[c], w1r[c], acc);
        hbuf[r] = fmaxf(acc, 0.f);
    }
    float logits[KK];
    float m = -1e30f;
    for (int k = 0; k < KK; ++k) {
        float acc = b2[k];
        const float* w2k = w2 + k * RED;
        for (int r = 0; r < RED; ++r) acc = fmaf(hbuf[r], w2k[r], acc);
        logits[k] = acc;
        m = fmaxf(m, acc);
    }
    float denom = 0.f;
    for (int k = 0; k < KK; ++k) { logits[k] = expf(logits[k] - m); denom += logits[k]; }
    float inv = 1.0f / denom;
    for (int k = 0; k < KK; ++k) att[b * KK + k] = logits[k] * inv;
}

// ---------------- Kernel 3: per-sample mixed conv ----------------
// grid = B(32) * sp(16) * og(8) = 4096 blocks, 256 threads.
// Block: sample b, 16x16 spatial tile, 32 output channels.
// Thread: tid = po*32 + pp;  po in [0,8): 4 o each;  pp in [0,32): 2x4 pixel sub-block.
// LDS: x halo tile [8c][18][19(pad)] + mixed weights [32o][8c][9].
#define CTILE 8
__global__ __launch_bounds__(256) void conv_kernel(const float* __restrict__ x,
                            const float* __restrict__ weights,
                            const float* __restrict__ att,
                            float* __restrict__ out) {
    __shared__ float xs[CTILE][18][19];
    __shared__ float wl[32][CTILE][9];

    int blk = blockIdx.x;
    int og = blk & 7;
    int sp = (blk >> 3) & 15;
    int b  = blk >> 7;

    int tr0 = (sp >> 2) * 16;
    int tc0 = (sp & 3) * 16;
    int o0  = og * 32;

    int tid = threadIdx.x;
    int po = tid >> 5;        // 0..7 -> o sub-group (4 o each)
    int pp = tid & 31;        // pixel sub-block
    int pr = pp >> 2;         // 0..7 -> rows pr*2, pr*2+1
    int pc = pp & 3;          // 0..3 -> cols pc*4 .. pc*4+3

    float a0 = att[b * KK + 0];
    float a1 = att[b * KK + 1];
    float a2 = att[b * KK + 2];
    float a3 = att[b * KK + 3];

    float acc[4][8];
#pragma unroll
    for (int oo = 0; oo < 4; ++oo)
#pragma unroll
        for (int p = 0; p < 8; ++p) acc[oo][p] = 0.f;

    const float* xb = x + (size_t)b * CC * HWSZ;

    for (int cc0 = 0; cc0 < CC; cc0 += CTILE) {
        __syncthreads();
        // ---- stage x halo tile: CTILE*18*18 = 2592 elems ----
        for (int idx = tid; idx < CTILE * 18 * 18; idx += 256) {
            int c = idx / 324;
            int rem = idx - c * 324;
            int r = rem / 18;
            int col = rem - r * 18;
            int gr = tr0 - 1 + r;
            int gc = tc0 - 1 + col;
            float v = 0.f;
            if (gr >= 0 && gr < HH && gc >= 0 && gc < WW)
                v = xb[(size_t)(cc0 + c) * HWSZ + gr * WW + gc];
            xs[c][r][col] = v;
        }
        // ---- stage mixed weights: 32*CTILE*9 = 2304 elems ----
        for (int idx = tid; idx < 32 * CTILE * 9; idx += 256) {
            int o = idx / (CTILE * 9);
            int rem = idx - o * (CTILE * 9);
            int c = rem / 9;
            int t = rem - c * 9;
            size_t base = ((size_t)(o0 + o) * CC + (cc0 + c)) * 9 + t;
            float v = a0 * weights[base]
                    + a1 * weights[base + KSTRIDE]
                    + a2 * weights[base + 2 * (size_t)KSTRIDE]
                    + a3 * weights[base + 3 * (size_t)KSTRIDE];
            wl[o][c][t] = v;
        }
        __syncthreads();

        // ---- compute ----
#pragma unroll
        for (int c = 0; c < CTILE; ++c) {
            float xv[4][6];
#pragma unroll
            for (int r = 0; r < 4; ++r)
#pragma unroll
                for (int q = 0; q < 6; ++q)
                    xv[r][q] = xs[c][pr * 2 + r][pc * 4 + q];
#pragma unroll
            for (int oo = 0; oo < 4; ++oo) {
                float wv[9];
#pragma unroll
                for (int t = 0; t < 9; ++t) wv[t] = wl[po * 4 + oo][c][t];
#pragma unroll
                for (int dr = 0; dr < 2; ++dr)
#pragma unroll
                    for (int dc = 0; dc < 4; ++dc) {
                        float a = acc[oo][dr * 4 + dc];
#pragma unroll
                        for (int kh = 0; kh < 3; ++kh)
#pragma unroll
                            for (int kw = 0; kw < 3; ++kw)
                                a = fmaf(xv[dr + kh][dc + kw], wv[kh * 3 + kw], a);
                        acc[oo][dr * 4 + dc] = a;
                    }
            }
        }
    }

    // ---- epilogue: write 4 o x 2 rows x 4 cols per thread ----
#pragma unroll
    for (int oo = 0; oo < 4; ++oo) {
        int o_glob = o0 + po * 4 + oo;
#pragma unroll
        for (int dr = 0; dr < 2; ++dr) {
            int row = tr0 + pr * 2 + dr;
            int col = tc0 + pc * 4;
            float4 v = make_float4(acc[oo][dr * 4 + 0], acc[oo][dr * 4 + 1],
                                   acc[oo][dr * 4 + 2], acc[oo][dr * 4 + 3]);
            *(float4*)&out[(((size_t)b * OO + o_glob) * HH + row) * WW + col] = v;
        }
    }
}

extern "C" void kernel_launch(void* const* d_in, const int* in_sizes, int n_in,
                              void* d_out, int out_size, void* d_ws, size_t ws_size,
                              hipStream_t stream) {
    const float* x       = (const float*)d_in[0];
    const float* weights = (const float*)d_in[1];
    const float* w1      = (const float*)d_in[2];
    const float* b1      = (const float*)d_in[3];
    const float* w2      = (const float*)d_in[4];
    const float* b2      = (const float*)d_in[5];
    float* out = (float*)d_out;

    float* pooled = (float*)d_ws;            // B*C floats
    float* att    = pooled + BB * CC;        // B*K floats

    pool_kernel<<<BB * CC, 256, 0, stream>>>(x, pooled);
    att_kernel<<<1, 64, 0, stream>>>(pooled, w1, b1, w2, b2, att);
    conv_kernel<<<BB * 16 * 8, 256, 0, stream>>>(x, weights, att, out);
}

// Round 2
// 507.909 us; speedup vs baseline: 3.4740x; 3.4740x over previous
//
#include <hip/hip_runtime.h>
#include <math.h>

#define BB 32
#define CC 128
#define HH 64
#define WW 64
#define KK 4
#define OO 256
#define RED 32
#define HWSZ (HH*WW)

typedef __attribute__((ext_vector_type(8))) short bf16x8;
typedef __attribute__((ext_vector_type(4))) float f32x4;

static __device__ __forceinline__ unsigned short f2bf(float f) {
    unsigned int u = __float_as_uint(f);
    u += 0x7FFF + ((u >> 16) & 1);   // round-to-nearest-even (finite inputs)
    return (unsigned short)(u >> 16);
}

// ---------------- Kernel 1: global average pool ----------------
__global__ void pool_kernel(const float* __restrict__ x, float* __restrict__ pooled) {
    int bc = blockIdx.x;
    const float4* p4 = (const float4*)(x + (size_t)bc * HWSZ);
    int tid = threadIdx.x;
    float s = 0.f;
    for (int i = tid; i < HWSZ / 4; i += 256) {
        float4 v = p4[i];
        s += v.x + v.y + v.z + v.w;
    }
    for (int off = 32; off > 0; off >>= 1) s += __shfl_down(s, off, 64);
    __shared__ float reds[4];
    int wid = tid >> 6, lane = tid & 63;
    if (lane == 0) reds[wid] = s;
    __syncthreads();
    if (tid == 0) pooled[bc] = (reds[0] + reds[1] + reds[2] + reds[3]) * (1.0f / HWSZ);
}

// ---------------- Kernel 2: MLP + softmax -> att[B][K] ----------------
__global__ void att_kernel(const float* __restrict__ pooled,
                           const float* __restrict__ w1, const float* __restrict__ b1,
                           const float* __restrict__ w2, const float* __restrict__ b2,
                           float* __restrict__ att) {
    int b = threadIdx.x;
    if (b >= BB) return;
    const float* pb = pooled + b * CC;
    float hbuf[RED];
    for (int r = 0; r < RED; ++r) {
        float acc = b1[r];
        const float* w1r = w1 + r * CC;
        for (int c = 0; c < CC; ++c) acc = fmaf(pb[c], w1r[c], acc);
        hbuf[r] = fmaxf(acc, 0.f);
    }
    float logits[KK];
    float m = -1e30f;
    for (int k = 0; k < KK; ++k) {
        float acc = b2[k];
        const float* w2k = w2 + k * RED;
        for (int r = 0; r < RED; ++r) acc = fmaf(hbuf[r], w2k[r], acc);
        logits[k] = acc;
        m = fmaxf(m, acc);
    }
    float denom = 0.f;
    for (int k = 0; k < KK; ++k) { logits[k] = expf(logits[k] - m); denom += logits[k]; }
    float inv = 1.0f / denom;
    for (int k = 0; k < KK; ++k) att[b * KK + k] = logits[k] * inv;
}

// ---------------- Kernel 3: mix weights -> bf16 wk[b][t][o][c] ----------------
// grid = 128 blocks x 256 threads; one thread per (o,c) pair, loops over b.
__global__ void mix_kernel(const float* __restrict__ w, const float* __restrict__ att,
                           unsigned short* __restrict__ wk) {
    int gid = blockIdx.x * 256 + threadIdx.x;   // 0..32767
    int o = gid >> 7, c = gid & 127;
    float wv[KK][9];
#pragma unroll
    for (int k = 0; k < KK; ++k) {
        const float* p = w + (((size_t)k * OO + o) * CC + c) * 9;
#pragma unroll
        for (int t = 0; t < 9; ++t) wv[k][t] = p[t];
    }
    for (int b = 0; b < BB; ++b) {
        float a0 = att[b * KK + 0], a1 = att[b * KK + 1];
        float a2 = att[b * KK + 2], a3 = att[b * KK + 3];
#pragma unroll
        for (int t = 0; t < 9; ++t) {
            float v = a0 * wv[0][t] + a1 * wv[1][t] + a2 * wv[2][t] + a3 * wv[3][t];
            wk[(((size_t)b * 9 + t) * OO + o) * CC + c] = f2bf(v);
        }
    }
}

// ---------------- Kernel 4: MFMA implicit-GEMM conv ----------------
// grid = 32 n-tiles x 2 o-tiles x 32 b = 2048 blocks, 256 threads (4 waves, 2x2).
// Block tile: 128 o x 128 px (2 rows x 64 cols). K-loop: 4 c-chunks x 9 taps.
// LDS: xs halo tile [4 rows][66 cols][32c pad->40], A-tile dbuf [2][128 o][32k pad->40].
#define XS_C 40
#define AL_C 40
__global__ __launch_bounds__(256, 3) void conv_mfma(const float* __restrict__ x,
                         const unsigned short* __restrict__ wk,
                         float* __restrict__ out) {
    __shared__ unsigned short xs[4 * 66 * XS_C];
    __shared__ unsigned short als[2][128 * AL_C];

    int blk = blockIdx.x;
    int nt = blk & 31;            // r0 = nt*2
    int ot = (blk >> 5) & 1;      // o0 = ot*128
    int b  = blk >> 6;
    int r0 = nt * 2;
    int o0 = ot * 128;

    int tid  = threadIdx.x;
    int lane = tid & 63;
    int wid  = tid >> 6;
    int wm   = wid & 1;           // o half (64)
    int wn   = wid >> 1;          // pixel row within tile (0/1)
    int l15  = lane & 15;
    int l4   = lane >> 4;

    f32x4 acc[4][4];
#pragma unroll
    for (int i = 0; i < 4; ++i)
#pragma unroll
        for (int j = 0; j < 4; ++j) acc[i][j] = (f32x4){0.f, 0.f, 0.f, 0.f};

    const float* xb = x + (size_t)b * CC * HWSZ;
    const unsigned short* wk_base = wk + ((size_t)b * 9 * OO + o0) * CC;

    for (int c0 = 0; c0 < CC; c0 += 32) {
        __syncthreads();
        // ---- stage x halo tile (fp32 -> bf16): 32c x 4rows x 66cols ----
        for (int i = tid; i < 32 * 4 * 66; i += 256) {
            int col = i % 66;
            int tmp = i / 66;
            int row = tmp & 3;
            int c   = tmp >> 2;
            int gr = r0 - 1 + row;
            int gc = col - 1;
            float v = 0.f;
            if ((unsigned)gr < HH && (unsigned)gc < WW)
                v = xb[(size_t)(c0 + c) * HWSZ + gr * WW + gc];
            xs[(row * 66 + col) * XS_C + c] = f2bf(v);
        }
        // ---- stage A(t=0) into buf 0: 128 o x 32 k, 16B chunks ----
        {
            int ch = tid;
#pragma unroll
            for (int rep = 0; rep < 2; ++rep, ch += 256) {
                int o = ch >> 2, seg = ch & 3;
                f32x4 v = *(const f32x4*)(wk_base + (size_t)o * CC + c0 + seg * 8);
                *(f32x4*)&als[0][o * AL_C + seg * 8] = v;
            }
        }
        __syncthreads();

        for (int t = 0; t < 9; ++t) {
            if (t < 8) {   // stage A(t+1) into the other buffer
                int tn = t + 1;
                int ch = tid;
#pragma unroll
                for (int rep = 0; rep < 2; ++rep, ch += 256) {
                    int o = ch >> 2, seg = ch & 3;
                    f32x4 v = *(const f32x4*)(wk_base + ((size_t)tn * OO + o) * CC + c0 + seg * 8);
                    *(f32x4*)&als[tn & 1][o * AL_C + seg * 8] = v;
                }
            }
            int kh = t / 3, kw = t - kh * 3;
            bf16x8 af[4], bfv[4];
#pragma unroll
            for (int mf = 0; mf < 4; ++mf)
                af[mf] = *(const bf16x8*)&als[t & 1][(wm * 64 + mf * 16 + l15) * AL_C + l4 * 8];
#pragma unroll
            for (int nf = 0; nf < 4; ++nf)
                bfv[nf] = *(const bf16x8*)&xs[((wn + kh) * 66 + (nf * 16 + l15 + kw)) * XS_C + l4 * 8];
#pragma unroll
            for (int mf = 0; mf < 4; ++mf)
#pragma unroll
                for (int nf = 0; nf < 4; ++nf)
                    acc[mf][nf] = __builtin_amdgcn_mfma_f32_16x16x32_bf16(
                        af[mf], bfv[nf], acc[mf][nf], 0, 0, 0);
            if (t < 8) __syncthreads();
        }
    }

    // ---- epilogue ----
    float* outb = out + ((size_t)b * OO + o0) * HWSZ;
    int prow = r0 + wn;
#pragma unroll
    for (int mf = 0; mf < 4; ++mf)
#pragma unroll
        for (int nf = 0; nf < 4; ++nf) {
            int pcol = nf * 16 + l15;
#pragma unroll
            for (int r = 0; r < 4; ++r) {
                int o = wm * 64 + mf * 16 + l4 * 4 + r;
                outb[(size_t)o * HWSZ + prow * WW + pcol] = acc[mf][nf][r];
            }
        }
}

extern "C" void kernel_launch(void* const* d_in, const int* in_sizes, int n_in,
                              void* d_out, int out_size, void* d_ws, size_t ws_size,
                              hipStream_t stream) {
    const float* x       = (const float*)d_in[0];
    const float* weights = (const float*)d_in[1];
    const float* w1      = (const float*)d_in[2];
    const float* b1      = (const float*)d_in[3];
    const float* w2      = (const float*)d_in[4];
    const float* b2      = (const float*)d_in[5];
    float* out = (float*)d_out;

    float* pooled = (float*)d_ws;                 // 4096 floats
    float* att    = pooled + BB * CC;             // 128 floats
    unsigned short* wk = (unsigned short*)(att + BB * KK);  // 16B-aligned (4224 floats in)

    pool_kernel<<<BB * CC, 256, 0, stream>>>(x, pooled);
    att_kernel<<<1, 64, 0, stream>>>(pooled, w1, b1, w2, b2, att);
    mix_kernel<<<OO * CC / 256, 256, 0, stream>>>(weights, att, wk);
    conv_mfma<<<BB * 2 * 32, 256, 0, stream>>>(x, wk, out);
}

// Round 3
// 375.093 us; speedup vs baseline: 4.7041x; 1.3541x over previous
//
#include <hip/hip_runtime.h>
#include <math.h>

#define BB 32
#define CC 128
#define HH 64
#define WW 64
#define KK 4
#define OO 256
#define RED 32
#define HWSZ (HH*WW)
#define XT_W 66            // 64 + 2 halo, both rows and cols

typedef __attribute__((ext_vector_type(8))) short bf16x8;
typedef __attribute__((ext_vector_type(4))) float f32x4;

static __device__ __forceinline__ unsigned short f2bf(float f) {
    unsigned int u = __float_as_uint(f);
    u += 0x7FFF + ((u >> 16) & 1);   // RNE
    return (unsigned short)(u >> 16);
}

// ---------- Kernel 1: transpose x -> xt[b][row][col][c] (bf16, zero halo) + pooled sums ----------
// grid = B*H = 2048 blocks, 256 threads. Block (b,h) handles one input row across all c.
__global__ __launch_bounds__(256) void transpose_pool(const float* __restrict__ x,
        unsigned short* __restrict__ xt, float* __restrict__ pooled) {
    __shared__ float lt[CC][65];
    int h = blockIdx.x & 63;
    int b = blockIdx.x >> 6;
    int w = threadIdx.x & 63;
    int cq = threadIdx.x >> 6;           // 0..3
    const float* xb = x + ((size_t)b * CC * HH + h) * WW;
    for (int pass = 0; pass < 32; ++pass) {
        int c = pass * 4 + cq;
        float v = xb[(size_t)c * HWSZ + w];
        lt[c][w] = v;
        float s = v;
        for (int off = 32; off > 0; off >>= 1) s += __shfl_down(s, off, 64);
        if (w == 0) atomicAdd(pooled + b * CC + c, s);
    }
    __syncthreads();
    size_t rowbase = ((size_t)b * XT_W + (h + 1)) * XT_W;
    // interior: 64 cols x 128 c -> 1024 chunks of 16B
    for (int i = threadIdx.x; i < 64 * 16; i += 256) {
        int ww = i >> 4, cs = i & 15;
        bf16x8 pk;
#pragma unroll
        for (int j = 0; j < 8; ++j) pk[j] = (short)f2bf(lt[cs * 8 + j][ww]);
        *(bf16x8*)&xt[(rowbase + (ww + 1)) * CC + cs * 8] = pk;
    }
    // col halo (cols 0 and 65) for this row
    if (threadIdx.x < 32) {
        int cs = threadIdx.x & 15;
        int col = (threadIdx.x < 16) ? 0 : 65;
        *(f32x4*)&xt[(rowbase + col) * CC + cs * 8] = (f32x4){0.f, 0.f, 0.f, 0.f};
    }
    // row halo (rows 0 and 65)
    if (h == 0 || h == 63) {
        int hr = (h == 0) ? 0 : 65;
        size_t rb = ((size_t)b * XT_W + hr) * XT_W;
        for (int i = threadIdx.x; i < XT_W * 16; i += 256) {
            int px = i >> 4, cs = i & 15;
            *(f32x4*)&xt[(rb + px) * CC + cs * 8] = (f32x4){0.f, 0.f, 0.f, 0.f};
        }
    }
}

// ---------- Kernel 2: MLP + softmax -> att[B][K] (parallel) ----------
// grid = 32 blocks (one per sample), 256 threads: tid = r*8 + j, j sums 16 c's.
__global__ void att_kernel(const float* __restrict__ pooled,
        const float* __restrict__ w1, const float* __restrict__ b1,
        const float* __restrict__ w2, const float* __restrict__ b2,
        float* __restrict__ att) {
    int b = blockIdx.x;
    int tid = threadIdx.x;
    int r = tid >> 3, j = tid & 7;
    __shared__ float hs[RED];
    __shared__ float ls[KK];
    const float* pbj = pooled + b * CC + j * 16;
    const float* w1r = w1 + r * CC + j * 16;
    float p = 0.f;
#pragma unroll
    for (int c = 0; c < 16; ++c) p = fmaf(pbj[c], w1r[c], p);
    p += __shfl_xor(p, 1, 64);
    p += __shfl_xor(p, 2, 64);
    p += __shfl_xor(p, 4, 64);
    if (j == 0) hs[r] = fmaxf(fmaf(p, 1.0f / (float)HWSZ, b1[r]), 0.f);
    __syncthreads();
    if (tid < KK) {
        float acc = b2[tid];
        const float* w2k = w2 + tid * RED;
#pragma unroll
        for (int rr = 0; rr < RED; ++rr) acc = fmaf(hs[rr], w2k[rr], acc);
        ls[tid] = acc;
    }
    __syncthreads();
    if (tid == 0) {
        float m = fmaxf(fmaxf(ls[0], ls[1]), fmaxf(ls[2], ls[3]));
        float e0 = expf(ls[0] - m), e1 = expf(ls[1] - m);
        float e2 = expf(ls[2] - m), e3 = expf(ls[3] - m);
        float inv = 1.0f / (e0 + e1 + e2 + e3);
        att[b * KK + 0] = e0 * inv; att[b * KK + 1] = e1 * inv;
        att[b * KK + 2] = e2 * inv; att[b * KK + 3] = e3 * inv;
    }
}

// ---------- Kernel 3: mix weights -> bf16 wk[b][t][o][c] ----------
// one thread per (b,o,c); grid = 32*256*128/256 = 4096 blocks.
__global__ __launch_bounds__(256) void mix_kernel(const float* __restrict__ w,
        const float* __restrict__ att, unsigned short* __restrict__ wk) {
    int gid = blockIdx.x * 256 + threadIdx.x;
    int c = gid & 127;
    int o = (gid >> 7) & 255;
    int b = gid >> 15;
    float a[KK];
#pragma unroll
    for (int k = 0; k < KK; ++k) a[k] = att[b * KK + k];
    float mixed[9];
#pragma unroll
    for (int t = 0; t < 9; ++t) mixed[t] = 0.f;
#pragma unroll
    for (int k = 0; k < KK; ++k) {
        const float* p = w + (((size_t)k * OO + o) * CC + c) * 9;
#pragma unroll
        for (int t = 0; t < 9; ++t) mixed[t] = fmaf(a[k], p[t], mixed[t]);
    }
#pragma unroll
    for (int t = 0; t < 9; ++t)
        wk[(((size_t)b * 9 + t) * OO + o) * CC + c] = f2bf(mixed[t]);
}

// ---------- Kernel 4: MFMA implicit-GEMM conv ----------
// grid = 32 b x 2 ot x 16 rg = 1024 blocks, 256 threads (4 waves).
// Block tile: 128 o x 256 px (4 rows x 64 cols). Wave: 64 o x 128 px -> 32 MFMA/stage.
// LDS: xs [6 rows x 66 cols][pad 40 shorts] + A dbuf [2][128][40].
#define XS_C 40
#define AL_C 40
__global__ __launch_bounds__(256, 2) void conv_mfma(const unsigned short* __restrict__ xt,
        const unsigned short* __restrict__ wk, float* __restrict__ out) {
    __shared__ unsigned short xs[6 * 66 * XS_C];     // 31680 B
    __shared__ unsigned short als[2][128 * AL_C];    // 20480 B

    int blk = blockIdx.x;
    int rg = blk & 15;
    int ot = (blk >> 4) & 1;
    int b  = blk >> 5;
    int r0 = rg * 4;
    int o0 = ot * 128;

    int tid = threadIdx.x;
    int lane = tid & 63;
    int wid = tid >> 6;
    int wm = wid & 1;         // o half
    int wn = wid >> 1;        // row pair (rows wn*2, wn*2+1 of the 4-row group)
    int l15 = lane & 15;
    int l4 = lane >> 4;

    f32x4 acc[4][8];
#pragma unroll
    for (int i = 0; i < 4; ++i)
#pragma unroll
        for (int j = 0; j < 8; ++j) acc[i][j] = (f32x4){0.f, 0.f, 0.f, 0.f};

    const unsigned short* xtb = xt + ((size_t)b * XT_W + r0) * XT_W * CC;
    const unsigned short* wk_base = wk + ((size_t)b * 9 * OO + o0) * CC;

    for (int c0 = 0; c0 < CC; c0 += 32) {
        __syncthreads();
        // stage xs: 6 rows x 66 cols x 32 c = 1584 x 16B chunks (pure aligned copies)
        for (int i = tid; i < 1584; i += 256) {
            int pix = i >> 2, seg = i & 3;
            int row = pix / 66, col = pix - row * 66;
            f32x4 v = *(const f32x4*)(xtb + ((size_t)row * XT_W + col) * CC + c0 + seg * 8);
            *(f32x4*)&xs[(size_t)pix * XS_C + seg * 8] = v;
        }
        // stage A(t=0)
        {
            int ch = tid;
#pragma unroll
            for (int rep = 0; rep < 2; ++rep, ch += 256) {
                int o = ch >> 2, seg = ch & 3;
                f32x4 v = *(const f32x4*)(wk_base + (size_t)o * CC + c0 + seg * 8);
                *(f32x4*)&als[0][o * AL_C + seg * 8] = v;
            }
        }
        __syncthreads();

        for (int t = 0; t < 9; ++t) {
            if (t < 8) {
                int tn = t + 1;
                int ch = tid;
#pragma unroll
                for (int rep = 0; rep < 2; ++rep, ch += 256) {
                    int o = ch >> 2, seg = ch & 3;
                    f32x4 v = *(const f32x4*)(wk_base + ((size_t)tn * OO + o) * CC + c0 + seg * 8);
                    *(f32x4*)&als[tn & 1][o * AL_C + seg * 8] = v;
                }
            }
            int kh = t / 3, kw = t - kh * 3;
            bf16x8 af[4], bfv[8];
#pragma unroll
            for (int mf = 0; mf < 4; ++mf)
                af[mf] = *(const bf16x8*)&als[t & 1][(wm * 64 + mf * 16 + l15) * AL_C + l4 * 8];
#pragma unroll
            for (int nf = 0; nf < 8; ++nf) {
                int prow = wn * 2 + (nf >> 2) + kh;
                int pcol = (nf & 3) * 16 + l15 + kw;
                bfv[nf] = *(const bf16x8*)&xs[(prow * 66 + pcol) * XS_C + l4 * 8];
            }
#pragma unroll
            for (int mf = 0; mf < 4; ++mf)
#pragma unroll
                for (int nf = 0; nf < 8; ++nf)
                    acc[mf][nf] = __builtin_amdgcn_mfma_f32_16x16x32_bf16(
                        af[mf], bfv[nf], acc[mf][nf], 0, 0, 0);
            if (t < 8) __syncthreads();
        }
    }

    // epilogue
    float* outb = out + ((size_t)b * OO + o0) * HWSZ;
#pragma unroll
    for (int mf = 0; mf < 4; ++mf)
#pragma unroll
        for (int nf = 0; nf < 8; ++nf) {
            int row = r0 + wn * 2 + (nf >> 2);
            int col = (nf & 3) * 16 + l15;
#pragma unroll
            for (int r = 0; r < 4; ++r) {
                int o = wm * 64 + mf * 16 + l4 * 4 + r;
                outb[(size_t)o * HWSZ + row * WW + col] = acc[mf][nf][r];
            }
        }
}

extern "C" void kernel_launch(void* const* d_in, const int* in_sizes, int n_in,
                              void* d_out, int out_size, void* d_ws, size_t ws_size,
                              hipStream_t stream) {
    const float* x       = (const float*)d_in[0];
    const float* weights = (const float*)d_in[1];
    const float* w1      = (const float*)d_in[2];
    const float* b1      = (const float*)d_in[3];
    const float* w2      = (const float*)d_in[4];
    const float* b2      = (const float*)d_in[5];
    float* out = (float*)d_out;

    char* ws = (char*)d_ws;
    float* pooled       = (float*)ws;                              // 16 KB (sums)
    float* att          = (float*)(ws + 16384);                    // 512 B
    unsigned short* wk  = (unsigned short*)(ws + 32768);           // 18.87 MB
    unsigned short* xtp = (unsigned short*)(ws + 32768 + 18874368);// 35.68 MB

    hipMemsetAsync(pooled, 0, BB * CC * sizeof(float), stream);
    transpose_pool<<<BB * HH, 256, 0, stream>>>(x, xtp, pooled);
    att_kernel<<<BB, 256, 0, stream>>>(pooled, w1, b1, w2, b2, att);
    mix_kernel<<<BB * OO * CC / 256, 256, 0, stream>>>(weights, att, wk);
    conv_mfma<<<BB * 2 * 16, 256, 0, stream>>>(xtp, wk, out);
}

// Round 4
// 296.236 us; speedup vs baseline: 5.9563x; 1.2662x over previous
//
#include <hip/hip_runtime.h>
#include <math.h>

#define BB 32
#define CC 128
#define HH 64
#define WW 64
#define KK 4
#define OO 256
#define RED 32
#define HWSZ (HH*WW)
#define XT_W 66            // 64 + 2 halo, both rows and cols

typedef __attribute__((ext_vector_type(8))) short bf16x8;
typedef __attribute__((ext_vector_type(4))) float f32x4;

static __device__ __forceinline__ unsigned short f2bf(float f) {
    unsigned int u = __float_as_uint(f);
    u += 0x7FFF + ((u >> 16) & 1);   // RNE
    return (unsigned short)(u >> 16);
}

// ---------- Kernel 1: transpose x -> xt[b][row][col][c] (bf16, zero halo) + per-(b,h) pool partials ----------
// grid = B*H = 2048 blocks, 256 threads. Block (b,h): one input row across all c.
// Phase 1: float4 global loads -> LDS (no deps, full MLP). Phase 2: pack bf16 + store.
// Phase 3: column-sum LDS -> partial[b*64+h][c]  (no atomics).
__global__ __launch_bounds__(256) void transpose_pool(const float* __restrict__ x,
        unsigned short* __restrict__ xt, float* __restrict__ partial) {
    __shared__ float lt[CC][65];
    int h = blockIdx.x & 63;
    int b = blockIdx.x >> 6;
    const float* xb = x + ((size_t)b * CC * HH + h) * WW;
    // phase 1: 128 c x 16 float4 = 2048 chunks, 8 per thread, all independent
    for (int i = threadIdx.x; i < CC * 16; i += 256) {
        int c = i >> 4, f4 = i & 15;
        float4 v = *(const float4*)(xb + (size_t)c * HWSZ + f4 * 4);
        lt[c][f4 * 4 + 0] = v.x;
        lt[c][f4 * 4 + 1] = v.y;
        lt[c][f4 * 4 + 2] = v.z;
        lt[c][f4 * 4 + 3] = v.w;
    }
    __syncthreads();
    size_t rowbase = ((size_t)b * XT_W + (h + 1)) * XT_W;
    // phase 2: pack interior: 64 cols x 16 c-groups -> 16B stores
    for (int i = threadIdx.x; i < 64 * 16; i += 256) {
        int ww = i >> 4, cs = i & 15;
        bf16x8 pk;
#pragma unroll
        for (int j = 0; j < 8; ++j) pk[j] = (short)f2bf(lt[cs * 8 + j][ww]);
        *(bf16x8*)&xt[(rowbase + (ww + 1)) * CC + cs * 8] = pk;
    }
    // col halo (cols 0 and 65) for this row
    if (threadIdx.x < 32) {
        int cs = threadIdx.x & 15;
        int col = (threadIdx.x < 16) ? 0 : 65;
        *(f32x4*)&xt[(rowbase + col) * CC + cs * 8] = (f32x4){0.f, 0.f, 0.f, 0.f};
    }
    // row halo (rows 0 and 65)
    if (h == 0 || h == 63) {
        int hr = (h == 0) ? 0 : 65;
        size_t rb = ((size_t)b * XT_W + hr) * XT_W;
        for (int i = threadIdx.x; i < XT_W * 16; i += 256) {
            int px = i >> 4, cs = i & 15;
            *(f32x4*)&xt[(rb + px) * CC + cs * 8] = (f32x4){0.f, 0.f, 0.f, 0.f};
        }
    }
    // phase 3: pooling partial for this (b,h): threads 0..127 sum their c column
    if (threadIdx.x < CC) {
        float s = 0.f;
#pragma unroll
        for (int j = 0; j < WW; ++j) s += lt[threadIdx.x][j];   // stride-65 rows: conflict-free
        partial[(size_t)blockIdx.x * CC + threadIdx.x] = s;
    }
}

// ---------- Kernel 2: h-reduce partials + MLP + softmax -> att[B][K] ----------
// grid = 32 blocks (one per sample), 256 threads.
__global__ void att_kernel(const float* __restrict__ partial,
        const float* __restrict__ w1, const float* __restrict__ b1,
        const float* __restrict__ w2, const float* __restrict__ b2,
        float* __restrict__ att) {
    int b = blockIdx.x;
    int tid = threadIdx.x;
    __shared__ float ps[CC];
    __shared__ float hs[RED];
    __shared__ float ls[KK];
    if (tid < CC) {
        const float* pp = partial + (size_t)b * HH * CC + tid;
        float s = 0.f;
#pragma unroll
        for (int h = 0; h < HH; ++h) s += pp[(size_t)h * CC];
        ps[tid] = s * (1.0f / (float)HWSZ);
    }
    __syncthreads();
    int r = tid >> 3, j = tid & 7;
    const float* w1r = w1 + r * CC + j * 16;
    float p = 0.f;
#pragma unroll
    for (int c = 0; c < 16; ++c) p = fmaf(ps[j * 16 + c], w1r[c], p);
    p += __shfl_xor(p, 1, 64);
    p += __shfl_xor(p, 2, 64);
    p += __shfl_xor(p, 4, 64);
    if (j == 0) hs[r] = fmaxf(p + b1[r], 0.f);
    __syncthreads();
    if (tid < KK) {
        float acc = b2[tid];
        const float* w2k = w2 + tid * RED;
#pragma unroll
        for (int rr = 0; rr < RED; ++rr) acc = fmaf(hs[rr], w2k[rr], acc);
        ls[tid] = acc;
    }
    __syncthreads();
    if (tid == 0) {
        float m = fmaxf(fmaxf(ls[0], ls[1]), fmaxf(ls[2], ls[3]));
        float e0 = expf(ls[0] - m), e1 = expf(ls[1] - m);
        float e2 = expf(ls[2] - m), e3 = expf(ls[3] - m);
        float inv = 1.0f / (e0 + e1 + e2 + e3);
        att[b * KK + 0] = e0 * inv; att[b * KK + 1] = e1 * inv;
        att[b * KK + 2] = e2 * inv; att[b * KK + 3] = e3 * inv;
    }
}

// ---------- Kernel 3: mix weights -> bf16 wk[b][t][o][c] ----------
__global__ __launch_bounds__(256) void mix_kernel(const float* __restrict__ w,
        const float* __restrict__ att, unsigned short* __restrict__ wk) {
    int gid = blockIdx.x * 256 + threadIdx.x;
    int c = gid & 127;
    int o = (gid >> 7) & 255;
    int b = gid >> 15;
    float a[KK];
#pragma unroll
    for (int k = 0; k < KK; ++k) a[k] = att[b * KK + k];
    float mixed[9];
#pragma unroll
    for (int t = 0; t < 9; ++t) mixed[t] = 0.f;
#pragma unroll
    for (int k = 0; k < KK; ++k) {
        const float* p = w + (((size_t)k * OO + o) * CC + c) * 9;
#pragma unroll
        for (int t = 0; t < 9; ++t) mixed[t] = fmaf(a[k], p[t], mixed[t]);
    }
#pragma unroll
    for (int t = 0; t < 9; ++t)
        wk[(((size_t)b * 9 + t) * OO + o) * CC + c] = f2bf(mixed[t]);
}

// ---------- Kernel 4: MFMA implicit-GEMM conv (unchanged from round 3) ----------
#define XS_C 40
#define AL_C 40
__global__ __launch_bounds__(256, 2) void conv_mfma(const unsigned short* __restrict__ xt,
        const unsigned short* __restrict__ wk, float* __restrict__ out) {
    __shared__ unsigned short xs[6 * 66 * XS_C];
    __shared__ unsigned short als[2][128 * AL_C];

    int blk = blockIdx.x;
    int rg = blk & 15;
    int ot = (blk >> 4) & 1;
    int b  = blk >> 5;
    int r0 = rg * 4;
    int o0 = ot * 128;

    int tid = threadIdx.x;
    int lane = tid & 63;
    int wid = tid >> 6;
    int wm = wid & 1;
    int wn = wid >> 1;
    int l15 = lane & 15;
    int l4 = lane >> 4;

    f32x4 acc[4][8];
#pragma unroll
    for (int i = 0; i < 4; ++i)
#pragma unroll
        for (int j = 0; j < 8; ++j) acc[i][j] = (f32x4){0.f, 0.f, 0.f, 0.f};

    const unsigned short* xtb = xt + ((size_t)b * XT_W + r0) * XT_W * CC;
    const unsigned short* wk_base = wk + ((size_t)b * 9 * OO + o0) * CC;

    for (int c0 = 0; c0 < CC; c0 += 32) {
        __syncthreads();
        for (int i = tid; i < 1584; i += 256) {
            int pix = i >> 2, seg = i & 3;
            int row = pix / 66, col = pix - row * 66;
            f32x4 v = *(const f32x4*)(xtb + ((size_t)row * XT_W + col) * CC + c0 + seg * 8);
            *(f32x4*)&xs[(size_t)pix * XS_C + seg * 8] = v;
        }
        {
            int ch = tid;
#pragma unroll
            for (int rep = 0; rep < 2; ++rep, ch += 256) {
                int o = ch >> 2, seg = ch & 3;
                f32x4 v = *(const f32x4*)(wk_base + (size_t)o * CC + c0 + seg * 8);
                *(f32x4*)&als[0][o * AL_C + seg * 8] = v;
            }
        }
        __syncthreads();

        for (int t = 0; t < 9; ++t) {
            if (t < 8) {
                int tn = t + 1;
                int ch = tid;
#pragma unroll
                for (int rep = 0; rep < 2; ++rep, ch += 256) {
                    int o = ch >> 2, seg = ch & 3;
                    f32x4 v = *(const f32x4*)(wk_base + ((size_t)tn * OO + o) * CC + c0 + seg * 8);
                    *(f32x4*)&als[tn & 1][o * AL_C + seg * 8] = v;
                }
            }
            int kh = t / 3, kw = t - kh * 3;
            bf16x8 af[4], bfv[8];
#pragma unroll
            for (int mf = 0; mf < 4; ++mf)
                af[mf] = *(const bf16x8*)&als[t & 1][(wm * 64 + mf * 16 + l15) * AL_C + l4 * 8];
#pragma unroll
            for (int nf = 0; nf < 8; ++nf) {
                int prow = wn * 2 + (nf >> 2) + kh;
                int pcol = (nf & 3) * 16 + l15 + kw;
                bfv[nf] = *(const bf16x8*)&xs[(prow * 66 + pcol) * XS_C + l4 * 8];
            }
#pragma unroll
            for (int mf = 0; mf < 4; ++mf)
#pragma unroll
                for (int nf = 0; nf < 8; ++nf)
                    acc[mf][nf] = __builtin_amdgcn_mfma_f32_16x16x32_bf16(
                        af[mf], bfv[nf], acc[mf][nf], 0, 0, 0);
            if (t < 8) __syncthreads();
        }
    }

    float* outb = out + ((size_t)b * OO + o0) * HWSZ;
#pragma unroll
    for (int mf = 0; mf < 4; ++mf)
#pragma unroll
        for (int nf = 0; nf < 8; ++nf) {
            int row = r0 + wn * 2 + (nf >> 2);
            int col = (nf & 3) * 16 + l15;
#pragma unroll
            for (int r = 0; r < 4; ++r) {
                int o = wm * 64 + mf * 16 + l4 * 4 + r;
                outb[(size_t)o * HWSZ + row * WW + col] = acc[mf][nf][r];
            }
        }
}

extern "C" void kernel_launch(void* const* d_in, const int* in_sizes, int n_in,
                              void* d_out, int out_size, void* d_ws, size_t ws_size,
                              hipStream_t stream) {
    const float* x       = (const float*)d_in[0];
    const float* weights = (const float*)d_in[1];
    const float* w1      = (const float*)d_in[2];
    const float* b1      = (const float*)d_in[3];
    const float* w2      = (const float*)d_in[4];
    const float* b2      = (const float*)d_in[5];
    float* out = (float*)d_out;

    char* ws = (char*)d_ws;
    float* partial      = (float*)ws;                               // 2048*128*4 = 1 MB
    float* att          = (float*)(ws + 1048576);                   // 512 B
    unsigned short* wk  = (unsigned short*)(ws + 1048576 + 4096);   // 18.87 MB
    unsigned short* xtp = (unsigned short*)(ws + 1048576 + 4096 + 18874368); // 35.68 MB

    transpose_pool<<<BB * HH, 256, 0, stream>>>(x, xtp, partial);
    att_kernel<<<BB, 256, 0, stream>>>(partial, w1, b1, w2, b2, att);
    mix_kernel<<<BB * OO * CC / 256, 256, 0, stream>>>(weights, att, wk);
    conv_mfma<<<BB * 2 * 16, 256, 0, stream>>>(xtp, wk, out);
}